// Round 4
// baseline (127.403 us; speedup 1.0000x reference)
//
#include <hip/hip_runtime.h>
#include <math.h>

#define N_ROWS 4096
#define DIM 256
constexpr float INV_T = 10.0f;

#define NT 32                   // 4096 / 128 tiles per view side
#define NTILES 528              // NT*(NT+1)/2 upper-triangular tiles
#define TOTAL_BLOCKS (2 * NTILES)
#define BM 128
#define BK 64

typedef __attribute__((ext_vector_type(8))) short short8;   // bf16x8 MFMA operand
typedef __attribute__((ext_vector_type(4))) float floatx4;  // fp32x4 accumulator

typedef __attribute__((address_space(3))) unsigned int lds_uint;
typedef const __attribute__((address_space(1))) unsigned int glb_uint;

__device__ __forceinline__ unsigned short f2bf(float f) {
    unsigned int u = __float_as_uint(f);
    return (unsigned short)((u + 0x7FFFu + ((u >> 16) & 1u)) >> 16);  // RNE
}

// Kernel 1: one wave per row. L2-normalized bf16 rows of z_j -> R0, z_i -> R1,
// pos[r] = dot(zi_n, zj_n)*10. Also zeroes denom[8192] + completion counter.
__global__ __launch_bounds__(256) void normalize_kernel(
    const float* __restrict__ z_i, const float* __restrict__ z_j,
    unsigned short* __restrict__ R0, unsigned short* __restrict__ R1,
    float* __restrict__ pos, unsigned int* __restrict__ zero_region)
{
    int gid = blockIdx.x * 256 + threadIdx.x;
    if (gid < 2 * N_ROWS + 1) zero_region[gid] = 0u;   // denom + counter

    int wave = threadIdx.x >> 6;
    int lane = threadIdx.x & 63;
    int row = blockIdx.x * 4 + wave;

    float4 a = ((const float4*)(z_i + (size_t)row * DIM))[lane];
    float4 b = ((const float4*)(z_j + (size_t)row * DIM))[lane];

    float ssa = a.x*a.x + a.y*a.y + a.z*a.z + a.w*a.w;
    float ssb = b.x*b.x + b.y*b.y + b.z*b.z + b.w*b.w;
    float dab = a.x*b.x + a.y*b.y + a.z*b.z + a.w*b.w;
    #pragma unroll
    for (int off = 1; off < 64; off <<= 1) {
        ssa += __shfl_xor(ssa, off);
        ssb += __shfl_xor(ssb, off);
        dab += __shfl_xor(dab, off);
    }
    float ra = rsqrtf(ssa);
    float rb = rsqrtf(ssb);

    ushort4 ua, ub;
    ua.x = f2bf(a.x * ra); ua.y = f2bf(a.y * ra); ua.z = f2bf(a.z * ra); ua.w = f2bf(a.w * ra);
    ub.x = f2bf(b.x * rb); ub.y = f2bf(b.y * rb); ub.z = f2bf(b.z * rb); ub.w = f2bf(b.w * rb);
    ((ushort4*)(R1 + (size_t)row * DIM))[lane] = ua;   // zi_norm
    ((ushort4*)(R0 + (size_t)row * DIM))[lane] = ub;   // zj_norm

    if (lane == 0) pos[row] = dab * ra * rb * INV_T;
}

// Kernel 2: symmetric fused GEMM, upper-triangular 128x128 tiles.
// Staging: global_load_lds 16B (one-hop HBM/L2 -> LDS) with SOURCE-side XOR
// swizzle: LDS slot s holds chunk (s&7)^(row&7) of its row, so ds_read_b128
// fragment reads are conflict-free without padding (round-2 verified, 0 confl).
// Off-diagonal tiles add row-sums AND col-sums of exp(10*S).
// Completion counter ordered by s_waitcnt vmcnt(0) (NO threadfence -- round-2's
// buffer_wbl2 per block was the 91us bug); last block computes the loss.
__global__ __launch_bounds__(256, 5) void gemm_sym(
    const unsigned short* __restrict__ R0,
    const unsigned short* __restrict__ R1,
    float* __restrict__ denom,            // [2*N] fp32, counter after
    const float* __restrict__ pos,
    float* __restrict__ out)
{
    __shared__ unsigned short As[BM * BK];   // 16 KB (reused for epilogue scratch)
    __shared__ unsigned short Bs[BM * BK];   // 16 KB  -> exactly 32 KB total, 5 blocks/CU

    int view = blockIdx.y;
    const unsigned short* R = view ? R1 : R0;
    float* den = denom + view * N_ROWS;

    // triangular decode: blockIdx.x -> (by, bx), bx >= by
    int t = blockIdx.x;
    int by = 0;
    while (t >= NT - by) { t -= NT - by; ++by; }
    int bx = by + t;
    int rT = by * BM, cT = bx * BM;

    int tid = threadIdx.x;
    int lane = tid & 63;
    int wave = tid >> 6;
    int wy = wave >> 1, wx = wave & 1;
    int m = lane & 15, q = lane >> 4;

    floatx4 acc[4][4] = {};

    for (int kidx = 0; kidx < 4; ++kidx) {
        int k0 = kidx * BK;
        __syncthreads();
        #pragma unroll
        for (int stp = 0; stp < 4; ++stp) {
            int s = stp * 256 + tid;              // 16B slot id (128 rows x 8 slots)
            int row = s >> 3, p = s & 7;
            int cg = p ^ (row & 7);               // source chunk for this slot
            const unsigned short* ga = R + (size_t)(rT + row) * DIM + k0 + cg * 8;
            const unsigned short* gb = R + (size_t)(cT + row) * DIM + k0 + cg * 8;
            __builtin_amdgcn_global_load_lds((glb_uint*)ga, (lds_uint*)&As[s * 8], 16, 0, 0);
            __builtin_amdgcn_global_load_lds((glb_uint*)gb, (lds_uint*)&Bs[s * 8], 16, 0, 0);
        }
        __syncthreads();

        #pragma unroll
        for (int kk = 0; kk < 2; ++kk) {
            short8 af[4], bfr[4];
            #pragma unroll
            for (int tt = 0; tt < 4; ++tt) {
                int ra = wy * 64 + tt * 16 + m;
                af[tt] = *(const short8*)&As[(ra * 8 + ((kk * 4 + q) ^ (ra & 7))) * 8];
                int rb = wx * 64 + tt * 16 + m;
                bfr[tt] = *(const short8*)&Bs[(rb * 8 + ((kk * 4 + q) ^ (rb & 7))) * 8];
            }
            #pragma unroll
            for (int i = 0; i < 4; ++i)
                #pragma unroll
                for (int j = 0; j < 4; ++j)
                    acc[i][j] = __builtin_amdgcn_mfma_f32_16x16x32_bf16(af[i], bfr[j], acc[i][j], 0, 0, 0);
        }
    }

    // Epilogue. C/D layout: col = m, row = q*4 + r (m89/m91).
    float rs[4][4] = {};
    float cs[4] = {0.f, 0.f, 0.f, 0.f};
    #pragma unroll
    for (int i = 0; i < 4; ++i) {
        #pragma unroll
        for (int j = 0; j < 4; ++j) {
            int gcol = cT + wx * 64 + j * 16 + m;
            #pragma unroll
            for (int r = 0; r < 4; ++r) {
                int grow = rT + wy * 64 + i * 16 + q * 4 + r;
                float e = (grow == gcol) ? 0.0f : __expf(acc[i][j][r] * INV_T);
                rs[i][r] += e;
                cs[j] += e;
            }
        }
    }
    #pragma unroll
    for (int off = 1; off < 16; off <<= 1)
        #pragma unroll
        for (int i = 0; i < 4; ++i)
            #pragma unroll
            for (int r = 0; r < 4; ++r)
                rs[i][r] += __shfl_xor(rs[i][r], off);
    if (m == 0) {
        #pragma unroll
        for (int i = 0; i < 4; ++i)
            #pragma unroll
            for (int r = 0; r < 4; ++r)
                atomicAdd(&den[rT + wy * 64 + i * 16 + q * 4 + r], rs[i][r]);
    }
    if (bx != by) {   // off-diagonal: col sums feed the mirrored rows
        #pragma unroll
        for (int off = 16; off < 64; off <<= 1)
            #pragma unroll
            for (int j = 0; j < 4; ++j)
                cs[j] += __shfl_xor(cs[j], off);
        if (q == 0) {
            #pragma unroll
            for (int j = 0; j < 4; ++j)
                atomicAdd(&den[cT + wx * 64 + j * 16 + m], cs[j]);
        }
    }

    // Order prior device-scope atomics (vmcnt-tracked) before the counter RMW.
    asm volatile("s_waitcnt vmcnt(0)" ::: "memory");
    __syncthreads();
    int* lastFlag = (int*)As;            // As/Bs dead past this barrier
    float* red = (float*)As + 2;
    int* counter = (int*)(denom + 2 * N_ROWS);
    if (tid == 0) *lastFlag = (atomicAdd(counter, 1) == TOTAL_BLOCKS - 1);
    __syncthreads();
    if (*lastFlag) {
        float s = 0.f;
        for (int r = tid; r < 2 * N_ROWS; r += 256) {
            float p = pos[r & (N_ROWS - 1)];
            float d = __hip_atomic_load(&denom[r], __ATOMIC_RELAXED, __HIP_MEMORY_SCOPE_AGENT);
            s += __logf(d + __expf(p)) - p;
        }
        #pragma unroll
        for (int off = 1; off < 64; off <<= 1) s += __shfl_xor(s, off);
        if (lane == 0) red[wave] = s;
        __syncthreads();
        if (tid == 0) out[0] = (red[0] + red[1] + red[2] + red[3]) * (1.0f / (2 * N_ROWS));
    }
}

extern "C" void kernel_launch(void* const* d_in, const int* in_sizes, int n_in,
                              void* d_out, int out_size, void* d_ws, size_t ws_size,
                              hipStream_t stream) {
    const float* z_i = (const float*)d_in[0];
    const float* z_j = (const float*)d_in[1];
    char* ws = (char*)d_ws;
    unsigned short* R0 = (unsigned short*)ws;                        // 2 MB
    unsigned short* R1 = (unsigned short*)(ws + (2u << 20));         // 2 MB
    float* pos   = (float*)(ws + (4u << 20));                        // 16 KB
    float* denom = (float*)(ws + (4u << 20) + (64u << 10));          // 32 KB + counter

    normalize_kernel<<<N_ROWS / 4, 256, 0, stream>>>(z_i, z_j, R0, R1, pos,
                                                     (unsigned int*)denom);
    dim3 grid(NTILES, 2);
    gemm_sym<<<grid, 256, 0, stream>>>(R0, R1, denom, pos, (float*)d_out);
}

// Round 6
// 91.358 us; speedup vs baseline: 1.3946x; 1.3946x over previous
//
#include <hip/hip_runtime.h>
#include <math.h>

#define N_ROWS 4096
#define DIM 256
constexpr float INV_T = 10.0f;

#define NT 32                   // 4096 / 128 tiles per view side
#define NTILES 528              // NT*(NT+1)/2 upper-triangular tiles
#define BM 128
#define BK 64
#define PSTRIDE 512             // [2x128 row partials (per wx) | 2x128 col partials (per wy)]

typedef __attribute__((ext_vector_type(8))) short short8;   // bf16x8 MFMA operand
typedef __attribute__((ext_vector_type(4))) float floatx4;  // fp32x4 accumulator

__device__ __forceinline__ unsigned short f2bf(float f) {
    unsigned int u = __float_as_uint(f);
    return (unsigned short)((u + 0x7FFFu + ((u >> 16) & 1u)) >> 16);  // RNE
}

// Kernel 1: one wave per row. L2-normalized bf16 rows of z_j -> R0, z_i -> R1,
// pos[r] = dot(zi_n, zj_n)*10. Thread (0,0) zeroes the scalar output.
__global__ __launch_bounds__(256) void normalize_kernel(
    const float* __restrict__ z_i, const float* __restrict__ z_j,
    unsigned short* __restrict__ R0, unsigned short* __restrict__ R1,
    float* __restrict__ pos, float* __restrict__ out)
{
    if (blockIdx.x == 0 && threadIdx.x == 0) out[0] = 0.0f;

    int wave = threadIdx.x >> 6;
    int lane = threadIdx.x & 63;
    int row = blockIdx.x * 4 + wave;

    float4 a = ((const float4*)(z_i + (size_t)row * DIM))[lane];
    float4 b = ((const float4*)(z_j + (size_t)row * DIM))[lane];

    float ssa = a.x*a.x + a.y*a.y + a.z*a.z + a.w*a.w;
    float ssb = b.x*b.x + b.y*b.y + b.z*b.z + b.w*b.w;
    float dab = a.x*b.x + a.y*b.y + a.z*b.z + a.w*b.w;
    #pragma unroll
    for (int off = 1; off < 64; off <<= 1) {
        ssa += __shfl_xor(ssa, off);
        ssb += __shfl_xor(ssb, off);
        dab += __shfl_xor(dab, off);
    }
    float ra = rsqrtf(ssa);
    float rb = rsqrtf(ssb);

    ushort4 ua, ub;
    ua.x = f2bf(a.x * ra); ua.y = f2bf(a.y * ra); ua.z = f2bf(a.z * ra); ua.w = f2bf(a.w * ra);
    ub.x = f2bf(b.x * rb); ub.y = f2bf(b.y * rb); ub.z = f2bf(b.z * rb); ub.w = f2bf(b.w * rb);
    ((ushort4*)(R1 + (size_t)row * DIM))[lane] = ua;   // zi_norm
    ((ushort4*)(R0 + (size_t)row * DIM))[lane] = ub;   // zj_norm

    if (lane == 0) pos[row] = dab * ra * rb * INV_T;
}

// Kernel 2: symmetric fused GEMM, upper-triangular 128x128 tiles (x2 views).
// Staging: coalesced uint4 global loads -> XOR-swizzled ds_write_b128
// (chunk c of row r lands at slot c^(r&7)) -> conflict-free ds_read_b128.
// Epilogue: exp(10*S) with diagonal excluded; ROW partials per (tile, wx-wave)
// and COL partials per (tile, wy-wave), PLAIN coalesced stores, unique slot per
// wave (round-5 bug: both wx waves shared a row slot -> race). No atomics, no
// completion counter, no fence -- blocks just end.
__global__ __launch_bounds__(256) void gemm_sym(
    const unsigned short* __restrict__ R0,
    const unsigned short* __restrict__ R1,
    float* __restrict__ part)             // [2][NTILES][PSTRIDE]
{
    __shared__ unsigned short As[BM * BK];   // 16 KB
    __shared__ unsigned short Bs[BM * BK];   // 16 KB

    int view = blockIdx.y;
    const unsigned short* R = view ? R1 : R0;
    float* P = part + (size_t)(view * NTILES + blockIdx.x) * PSTRIDE;

    // triangular decode: blockIdx.x -> (by, bx), bx >= by
    int t = blockIdx.x;
    int by = 0;
    while (t >= NT - by) { t -= NT - by; ++by; }
    int bx = by + t;
    int rT = by * BM, cT = bx * BM;

    int tid = threadIdx.x;
    int lane = tid & 63;
    int wave = tid >> 6;
    int wy = wave >> 1, wx = wave & 1;
    int m = lane & 15, q = lane >> 4;

    floatx4 acc[4][4] = {};

    for (int kidx = 0; kidx < 4; ++kidx) {
        int k0 = kidx * BK;
        __syncthreads();
        #pragma unroll
        for (int it = 0; it < 4; ++it) {
            int s = it * 256 + tid;            // chunk id: 128 rows x 8 chunks
            int row = s >> 3, c = s & 7;
            uint4 va = *(const uint4*)(R + (size_t)(rT + row) * DIM + k0 + c * 8);
            uint4 vb = *(const uint4*)(R + (size_t)(cT + row) * DIM + k0 + c * 8);
            int slot = row * 8 + (c ^ (row & 7));
            *(uint4*)&As[slot * 8] = va;
            *(uint4*)&Bs[slot * 8] = vb;
        }
        __syncthreads();

        #pragma unroll
        for (int kk = 0; kk < 2; ++kk) {
            short8 af[4], bfr[4];
            #pragma unroll
            for (int tt = 0; tt < 4; ++tt) {
                int ra = wy * 64 + tt * 16 + m;
                af[tt] = *(const short8*)&As[(ra * 8 + ((kk * 4 + q) ^ (ra & 7))) * 8];
                int rb = wx * 64 + tt * 16 + m;
                bfr[tt] = *(const short8*)&Bs[(rb * 8 + ((kk * 4 + q) ^ (rb & 7))) * 8];
            }
            #pragma unroll
            for (int i = 0; i < 4; ++i)
                #pragma unroll
                for (int j = 0; j < 4; ++j)
                    acc[i][j] = __builtin_amdgcn_mfma_f32_16x16x32_bf16(af[i], bfr[j], acc[i][j], 0, 0, 0);
        }
    }

    // Epilogue. C/D layout: col = m, row = q*4 + r (m89/m91).
    float rs[4][4] = {};
    float cs[4] = {0.f, 0.f, 0.f, 0.f};
    #pragma unroll
    for (int i = 0; i < 4; ++i) {
        #pragma unroll
        for (int j = 0; j < 4; ++j) {
            int gcol = cT + wx * 64 + j * 16 + m;
            #pragma unroll
            for (int r = 0; r < 4; ++r) {
                int grow = rT + wy * 64 + i * 16 + q * 4 + r;
                float e = (grow == gcol) ? 0.0f : __expf(acc[i][j][r] * INV_T);
                rs[i][r] += e;
                cs[j] += e;
            }
        }
    }
    // Row partials: reduce over the 16 column-lanes (m); per-(wx,wy) slot.
    #pragma unroll
    for (int off = 1; off < 16; off <<= 1)
        #pragma unroll
        for (int i = 0; i < 4; ++i)
            #pragma unroll
            for (int r = 0; r < 4; ++r)
                rs[i][r] += __shfl_xor(rs[i][r], off);
    if (m == 0) {
        #pragma unroll
        for (int i = 0; i < 4; ++i) {
            float4 v = make_float4(rs[i][0], rs[i][1], rs[i][2], rs[i][3]);
            *(float4*)&P[wx * 128 + wy * 64 + i * 16 + q * 4] = v;
        }
    }
    // Col partials: reduce over the 4 row-quads (q); per-(wy,wx) slot.
    // Diagonal tiles store 0 (their block is fully covered by the row sums).
    #pragma unroll
    for (int off = 16; off < 64; off <<= 1)
        #pragma unroll
        for (int j = 0; j < 4; ++j)
            cs[j] += __shfl_xor(cs[j], off);
    if (q == 0) {
        #pragma unroll
        for (int j = 0; j < 4; ++j)
            P[256 + wy * 128 + wx * 64 + j * 16 + m] = (bx == by) ? 0.0f : cs[j];
    }
}

// Kernel 3: per-row denom gather (L2-resident) + loss reduce.
__global__ __launch_bounds__(256) void finalize_kernel(
    const float* __restrict__ part, const float* __restrict__ pos,
    float* __restrict__ out)
{
    int g = blockIdx.x * 256 + threadIdx.x;      // 0..8191
    int v = g >> 12, r = g & (N_ROWS - 1);
    int b = r >> 7, l = r & 127;
    const float* P = part + (size_t)v * NTILES * PSTRIDE;

    float d = 0.f;
    int t0 = b * NT - (b * (b - 1)) / 2;         // tile (b, b)
    for (int k = 0; k < NT - b; ++k) {           // row parts: tiles (b, bx>=b)
        const float* T = P + (size_t)(t0 + k) * PSTRIDE;
        d += T[l] + T[128 + l];                  // both wx halves
    }
    for (int by = 0; by <= b; ++by) {            // col parts: tiles (by<=b, b)
        int tb = by * NT - (by * (by - 1)) / 2 + (b - by);
        const float* T = P + (size_t)tb * PSTRIDE;
        d += T[256 + l] + T[384 + l];            // both wy halves
    }
    float p = pos[r];
    float s = __logf(d + __expf(p)) - p;
    #pragma unroll
    for (int off = 1; off < 64; off <<= 1) s += __shfl_xor(s, off);
    if ((threadIdx.x & 63) == 0)
        atomicAdd(out, s * (1.0f / (2 * N_ROWS)));
}

extern "C" void kernel_launch(void* const* d_in, const int* in_sizes, int n_in,
                              void* d_out, int out_size, void* d_ws, size_t ws_size,
                              hipStream_t stream) {
    const float* z_i = (const float*)d_in[0];
    const float* z_j = (const float*)d_in[1];
    char* ws = (char*)d_ws;
    unsigned short* R0 = (unsigned short*)ws;                        // 2 MB
    unsigned short* R1 = (unsigned short*)(ws + (2u << 20));         // 2 MB
    float* pos  = (float*)(ws + (4u << 20));                         // 16 KB
    float* part = (float*)(ws + (4u << 20) + (64u << 10));           // 2.1 MB

    normalize_kernel<<<N_ROWS / 4, 256, 0, stream>>>(z_i, z_j, R0, R1, pos,
                                                     (float*)d_out);
    dim3 grid(NTILES, 2);
    gemm_sym<<<grid, 256, 0, stream>>>(R0, R1, part);
    finalize_kernel<<<2 * N_ROWS / 256, 256, 0, stream>>>(part, pos, (float*)d_out);
}

// Round 7
// 89.833 us; speedup vs baseline: 1.4182x; 1.0170x over previous
//
#include <hip/hip_runtime.h>
#include <math.h>

#define N_ROWS 4096
#define DIM 256
constexpr float INV_T = 10.0f;

#define NT 32                   // 4096 / 128 tiles per view side
#define NTILES 528              // NT*(NT+1)/2 upper-triangular tiles
#define BM 128
#define BK 64
#define PSTRIDE 512             // [2x128 row partials (per wx) | 2x128 col partials (per wy)]

typedef __attribute__((ext_vector_type(8))) short short8;   // bf16x8 MFMA operand
typedef __attribute__((ext_vector_type(4))) float floatx4;  // fp32x4 accumulator

typedef __attribute__((address_space(3))) unsigned int lds_uint;
typedef const __attribute__((address_space(1))) unsigned int glb_uint;

__device__ __forceinline__ unsigned short f2bf(float f) {
    unsigned int u = __float_as_uint(f);
    return (unsigned short)((u + 0x7FFFu + ((u >> 16) & 1u)) >> 16);  // RNE
}

// Kernel 1: one wave per row. L2-normalized bf16 rows of z_j -> R0, z_i -> R1,
// pos[r] = dot(zi_n, zj_n)*10. Thread (0,0) zeroes the scalar output.
__global__ __launch_bounds__(256) void normalize_kernel(
    const float* __restrict__ z_i, const float* __restrict__ z_j,
    unsigned short* __restrict__ R0, unsigned short* __restrict__ R1,
    float* __restrict__ pos, float* __restrict__ out)
{
    if (blockIdx.x == 0 && threadIdx.x == 0) out[0] = 0.0f;

    int wave = threadIdx.x >> 6;
    int lane = threadIdx.x & 63;
    int row = blockIdx.x * 4 + wave;

    float4 a = ((const float4*)(z_i + (size_t)row * DIM))[lane];
    float4 b = ((const float4*)(z_j + (size_t)row * DIM))[lane];

    float ssa = a.x*a.x + a.y*a.y + a.z*a.z + a.w*a.w;
    float ssb = b.x*b.x + b.y*b.y + b.z*b.z + b.w*b.w;
    float dab = a.x*b.x + a.y*b.y + a.z*b.z + a.w*b.w;
    #pragma unroll
    for (int off = 1; off < 64; off <<= 1) {
        ssa += __shfl_xor(ssa, off);
        ssb += __shfl_xor(ssb, off);
        dab += __shfl_xor(dab, off);
    }
    float ra = rsqrtf(ssa);
    float rb = rsqrtf(ssb);

    ushort4 ua, ub;
    ua.x = f2bf(a.x * ra); ua.y = f2bf(a.y * ra); ua.z = f2bf(a.z * ra); ua.w = f2bf(a.w * ra);
    ub.x = f2bf(b.x * rb); ub.y = f2bf(b.y * rb); ub.z = f2bf(b.z * rb); ub.w = f2bf(b.w * rb);
    ((ushort4*)(R1 + (size_t)row * DIM))[lane] = ua;   // zi_norm
    ((ushort4*)(R0 + (size_t)row * DIM))[lane] = ub;   // zj_norm

    if (lane == 0) pos[row] = dab * ra * rb * INV_T;
}

// Kernel 2: symmetric fused GEMM, upper-triangular 128x128 tiles (x2 views).
// Staging: global_load_lds 16B one-hop (no VGPR temporaries -> arch VGPR ~64,
// unified 64+64acc = 128 -> 16 waves/CU bucket, 4 blocks/CU; round-2-verified
// source-side XOR swizzle: LDS slot s holds chunk (s&7)^(row&7) of its row,
// so ds_read_b128 fragment reads are conflict-free without padding).
// Epilogue: exp(10*S), diagonal excluded; ROW partials per (tile,wx-wave) and
// COL partials per (tile,wy-wave), plain coalesced stores, unique slot per
// wave. No atomics, no completion counter, no fence (round-2 wbl2 bug).
__global__ __launch_bounds__(256, 4) void gemm_sym(
    const unsigned short* __restrict__ R0,
    const unsigned short* __restrict__ R1,
    float* __restrict__ part)             // [2][NTILES][PSTRIDE]
{
    __shared__ unsigned short As[BM * BK];   // 16 KB
    __shared__ unsigned short Bs[BM * BK];   // 16 KB -> exactly 32 KB

    int view = blockIdx.y;
    const unsigned short* R = view ? R1 : R0;
    float* P = part + (size_t)(view * NTILES + blockIdx.x) * PSTRIDE;

    // triangular decode: blockIdx.x -> (by, bx), bx >= by
    int t = blockIdx.x;
    int by = 0;
    while (t >= NT - by) { t -= NT - by; ++by; }
    int bx = by + t;
    int rT = by * BM, cT = bx * BM;

    int tid = threadIdx.x;
    int lane = tid & 63;
    int wave = tid >> 6;
    int wy = wave >> 1, wx = wave & 1;
    int m = lane & 15, q = lane >> 4;

    floatx4 acc[4][4] = {};

    for (int kidx = 0; kidx < 4; ++kidx) {
        int k0 = kidx * BK;
        __syncthreads();
        #pragma unroll
        for (int stp = 0; stp < 4; ++stp) {
            int s = stp * 256 + tid;              // 16B slot id (128 rows x 8 slots)
            int row = s >> 3, p = s & 7;
            int cg = p ^ (row & 7);               // source chunk for this slot
            const unsigned short* ga = R + (size_t)(rT + row) * DIM + k0 + cg * 8;
            const unsigned short* gb = R + (size_t)(cT + row) * DIM + k0 + cg * 8;
            __builtin_amdgcn_global_load_lds((glb_uint*)ga, (lds_uint*)&As[s * 8], 16, 0, 0);
            __builtin_amdgcn_global_load_lds((glb_uint*)gb, (lds_uint*)&Bs[s * 8], 16, 0, 0);
        }
        __syncthreads();

        #pragma unroll
        for (int kk = 0; kk < 2; ++kk) {
            short8 af[4], bfr[4];
            #pragma unroll
            for (int tt = 0; tt < 4; ++tt) {
                int ra = wy * 64 + tt * 16 + m;
                af[tt] = *(const short8*)&As[(ra * 8 + ((kk * 4 + q) ^ (ra & 7))) * 8];
                int rb = wx * 64 + tt * 16 + m;
                bfr[tt] = *(const short8*)&Bs[(rb * 8 + ((kk * 4 + q) ^ (rb & 7))) * 8];
            }
            #pragma unroll
            for (int i = 0; i < 4; ++i)
                #pragma unroll
                for (int j = 0; j < 4; ++j)
                    acc[i][j] = __builtin_amdgcn_mfma_f32_16x16x32_bf16(af[i], bfr[j], acc[i][j], 0, 0, 0);
        }
    }

    // Epilogue. C/D layout: col = m, row = q*4 + r (m89/m91).
    float rs[4][4] = {};
    float cs[4] = {0.f, 0.f, 0.f, 0.f};
    #pragma unroll
    for (int i = 0; i < 4; ++i) {
        #pragma unroll
        for (int j = 0; j < 4; ++j) {
            int gcol = cT + wx * 64 + j * 16 + m;
            #pragma unroll
            for (int r = 0; r < 4; ++r) {
                int grow = rT + wy * 64 + i * 16 + q * 4 + r;
                float e = (grow == gcol) ? 0.0f : __expf(acc[i][j][r] * INV_T);
                rs[i][r] += e;
                cs[j] += e;
            }
        }
    }
    // Row partials: reduce over the 16 column-lanes (m); per-(wx,wy) slot.
    #pragma unroll
    for (int off = 1; off < 16; off <<= 1)
        #pragma unroll
        for (int i = 0; i < 4; ++i)
            #pragma unroll
            for (int r = 0; r < 4; ++r)
                rs[i][r] += __shfl_xor(rs[i][r], off);
    if (m == 0) {
        #pragma unroll
        for (int i = 0; i < 4; ++i) {
            float4 v = make_float4(rs[i][0], rs[i][1], rs[i][2], rs[i][3]);
            *(float4*)&P[wx * 128 + wy * 64 + i * 16 + q * 4] = v;
        }
    }
    // Col partials: reduce over the 4 row-quads (q); per-(wy,wx) slot.
    // Diagonal tiles store 0 (their block is fully covered by the row sums).
    #pragma unroll
    for (int off = 16; off < 64; off <<= 1)
        #pragma unroll
        for (int j = 0; j < 4; ++j)
            cs[j] += __shfl_xor(cs[j], off);
    if (q == 0) {
        #pragma unroll
        for (int j = 0; j < 4; ++j)
            P[256 + wy * 128 + wx * 64 + j * 16 + m] = (bx == by) ? 0.0f : cs[j];
    }
}

// Kernel 3: per-row denom gather (L2-resident) + loss reduce.
__global__ __launch_bounds__(256) void finalize_kernel(
    const float* __restrict__ part, const float* __restrict__ pos,
    float* __restrict__ out)
{
    int g = blockIdx.x * 256 + threadIdx.x;      // 0..8191
    int v = g >> 12, r = g & (N_ROWS - 1);
    int b = r >> 7, l = r & 127;
    const float* P = part + (size_t)v * NTILES * PSTRIDE;

    float d = 0.f;
    int t0 = b * NT - (b * (b - 1)) / 2;         // tile (b, b)
    for (int k = 0; k < NT - b; ++k) {           // row parts: tiles (b, bx>=b)
        const float* T = P + (size_t)(t0 + k) * PSTRIDE;
        d += T[l] + T[128 + l];                  // both wx halves
    }
    for (int by = 0; by <= b; ++by) {            // col parts: tiles (by<=b, b)
        int tb = by * NT - (by * (by - 1)) / 2 + (b - by);
        const float* T = P + (size_t)tb * PSTRIDE;
        d += T[256 + l] + T[384 + l];            // both wy halves
    }
    float p = pos[r];
    float s = __logf(d + __expf(p)) - p;
    #pragma unroll
    for (int off = 1; off < 64; off <<= 1) s += __shfl_xor(s, off);
    if ((threadIdx.x & 63) == 0)
        atomicAdd(out, s * (1.0f / (2 * N_ROWS)));
}

extern "C" void kernel_launch(void* const* d_in, const int* in_sizes, int n_in,
                              void* d_out, int out_size, void* d_ws, size_t ws_size,
                              hipStream_t stream) {
    const float* z_i = (const float*)d_in[0];
    const float* z_j = (const float*)d_in[1];
    char* ws = (char*)d_ws;
    unsigned short* R0 = (unsigned short*)ws;                        // 2 MB
    unsigned short* R1 = (unsigned short*)(ws + (2u << 20));         // 2 MB
    float* pos  = (float*)(ws + (4u << 20));                         // 16 KB
    float* part = (float*)(ws + (4u << 20) + (64u << 10));           // 2.1 MB

    normalize_kernel<<<N_ROWS / 4, 256, 0, stream>>>(z_i, z_j, R0, R1, pos,
                                                     (float*)d_out);
    dim3 grid(NTILES, 2);
    gemm_sym<<<grid, 256, 0, stream>>>(R0, R1, part);
    finalize_kernel<<<2 * N_ROWS / 256, 256, 0, stream>>>(part, pos, (float*)d_out);
}